// Round 1
// baseline (1341.812 us; speedup 1.0000x reference)
//
#include <hip/hip_runtime.h>

// Attention_18605798326350: B=2,S=2048,DIM=4096,H=32,KVH=8,HD=128, rope theta 5e5, causal.
// Strategy: cast all to bf16, m97-style MFMA GEMMs (NT: C=A*B^T, both row-major along K),
// RoPE fused in Q/K GEMM epilogue, flash attention with online softmax, final O GEMM -> fp32.

#define HN   32
#define KVHN 8
#define HDIM 128
#define SEQ  2048
#define NB   2
#define DIMM 4096
#define KVD  1024

typedef __attribute__((ext_vector_type(4))) float floatx4;
typedef __attribute__((ext_vector_type(8))) short bf16x8;   // 8 bf16 in 4 VGPRs (guide §3)
typedef unsigned short u16;
typedef unsigned int   u32;

__device__ __forceinline__ u16 f2bf(float f) {           // RNE fp32->bf16
  union { float f; u32 u; } x; x.f = f;
  u32 r = x.u + 0x7fffu + ((x.u >> 16) & 1u);
  return (u16)(r >> 16);
}

// async global->LDS, 16B per lane; LDS dest = wave-uniform base + lane*16 (guide §5 caveat)
__device__ __forceinline__ void gload_lds16(const u16* g, u16* l) {
  __builtin_amdgcn_global_load_lds(
      (const __attribute__((address_space(1))) void*)g,
      (__attribute__((address_space(3))) void*)l, 16, 0, 0);
}

__global__ __launch_bounds__(256) void cast_f2bf_kernel(const float* __restrict__ in,
                                                        u16* __restrict__ out, int n) {
  int i = (blockIdx.x * 256 + threadIdx.x) * 8;
  if (i + 8 > n) return;                       // n is always a multiple of 2048
  const float4* p = (const float4*)(in + i);
  float4 a = p[0], b = p[1];
  union { u16 h[8]; uint4 v; } r;
  r.h[0] = f2bf(a.x); r.h[1] = f2bf(a.y); r.h[2] = f2bf(a.z); r.h[3] = f2bf(a.w);
  r.h[4] = f2bf(b.x); r.h[5] = f2bf(b.y); r.h[6] = f2bf(b.z); r.h[7] = f2bf(b.w);
  *(uint4*)(out + i) = r.v;
}

// C[m,n] = sum_k A[m,k]*B[n,k].  EPI: 0 = bf16 store, 1 = bf16 + fused RoPE, 2 = fp32 store.
template <int EPI>
__global__ __launch_bounds__(256) void gemm_nt(const u16* __restrict__ A, const u16* __restrict__ B,
                                               void* __restrict__ Cv, int M, int N, int K,
                                               const float* __restrict__ fc, const float* __restrict__ fs) {
  __shared__ u16 lA[128 * 32];
  __shared__ u16 lB[128 * 32];
  const int tid = threadIdx.x;
  const int w = tid >> 6, l = tid & 63, g = l >> 4, c = l & 15;
  const int m0 = blockIdx.y * 128, n0 = blockIdx.x * 128;
  const int wm = w & 1, wn = w >> 1;
  floatx4 acc[4][4] = {};
  const u16* Ab = A + (long)m0 * K;
  const u16* Bb = B + (long)n0 * K;
  // staging geometry: call cc covers elems (cc*4+w)*512 + l*8 of the 128x32 tile
  const int off0 = w * 512 + l * 8;
  const int r0 = off0 >> 5, c0 = off0 & 31;
  const int off1 = off0 + 2048;
  const int r1 = off1 >> 5, c1 = off1 & 31;

  for (int kt = 0; kt < K; kt += 32) {
    __syncthreads();
    gload_lds16(Ab + (long)r0 * K + kt + c0, &lA[w * 512]);
    gload_lds16(Bb + (long)r0 * K + kt + c0, &lB[w * 512]);
    gload_lds16(Ab + (long)r1 * K + kt + c1, &lA[2048 + w * 512]);
    gload_lds16(Bb + (long)r1 * K + kt + c1, &lB[2048 + w * 512]);
    __syncthreads();
    bf16x8 af[4], bf[4];
#pragma unroll
    for (int i = 0; i < 4; ++i) af[i] = *(const bf16x8*)&lA[(wm * 64 + i * 16 + c) * 32 + g * 8];
#pragma unroll
    for (int j = 0; j < 4; ++j) bf[j] = *(const bf16x8*)&lB[(wn * 64 + j * 16 + c) * 32 + g * 8];
#pragma unroll
    for (int i = 0; i < 4; ++i)
#pragma unroll
      for (int j = 0; j < 4; ++j)
        acc[i][j] = __builtin_amdgcn_mfma_f32_16x16x32_bf16(af[i], bf[j], acc[i][j], 0, 0, 0);
  }

#pragma unroll
  for (int i = 0; i < 4; ++i)
#pragma unroll
    for (int j = 0; j < 4; ++j)
#pragma unroll
      for (int r = 0; r < 4; ++r) {
        int row = m0 + wm * 64 + i * 16 + g * 4 + r;   // C-layout: row=(lane>>4)*4+reg
        int col = n0 + wn * 64 + j * 16 + c;           //           col=lane&15
        float v = acc[i][j][r];
        if (EPI == 1) {
          // interleaved RoPE: pairs (2i,2i+1) within each 128-wide head; partner = lane^1
          float pv = __shfl_xor(v, 1);
          int pos = row & (SEQ - 1);
          int fi = (col & (HDIM - 1)) >> 1;
          float cs = fc[pos * (HDIM / 2) + fi];
          float sn = fs[pos * (HDIM / 2) + fi];
          v = (col & 1) ? (pv * sn + v * cs) : (v * cs - pv * sn);
        }
        if (EPI == 2) ((float*)Cv)[(long)row * N + col] = v;
        else          ((u16*)Cv)[(long)row * N + col] = f2bf(v);
      }
}

// Flash attention: grid (S/128, B*H). BQ=128, BK=64. 4 waves x 32 q-rows each.
__global__ __launch_bounds__(256) void flash_attn(const u16* __restrict__ q, const u16* __restrict__ kk,
                                                  const u16* __restrict__ vv, u16* __restrict__ o) {
  __shared__ u16 sKV[16384];        // Q tile (once) then K[0:8192) | V[8192:16384)
  __shared__ u16 sP[128 * 64];      // P round-trip (C-layout -> A-layout, m120 pattern)
  const int tid = threadIdx.x;
  const int w = tid >> 6, l = tid & 63, g = l >> 4, c = l & 15;
  const int bh = blockIdx.y, b = bh >> 5, h = bh & 31, kvh = h >> 2;
  const int q0 = blockIdx.x * 128;

  { // stage Q tile 128x128 (32KB, 8 workgroup calls)
    const u16* qg = q + (long)(b * SEQ + q0) * DIMM + h * HDIM;
#pragma unroll
    for (int cc = 0; cc < 8; ++cc) {
      int off = (cc * 4 + w) * 512 + l * 8;
      int row = off >> 7, col = off & 127;
      gload_lds16(qg + (long)row * DIMM + col, &sKV[(cc * 4 + w) * 512]);
    }
  }
  __syncthreads();
  bf16x8 qf[2][4];
#pragma unroll
  for (int i = 0; i < 2; ++i) {
    int m_loc = w * 32 + i * 16 + c;
#pragma unroll
    for (int t = 0; t < 4; ++t)
      qf[i][t] = *(const bf16x8*)&sKV[m_loc * 128 + t * 32 + g * 8];
  }

  floatx4 oacc[2][8] = {};
  float mrow[2][4], lrow[2][4];
#pragma unroll
  for (int i = 0; i < 2; ++i)
#pragma unroll
    for (int r = 0; r < 4; ++r) { mrow[i][r] = -1e30f; lrow[i][r] = 0.f; }

  const int nkt = (q0 + 128) / 64;            // causal: skip tiles fully above diagonal
  const u16* kg = kk + (long)b * SEQ * KVD + kvh * HDIM;
  const u16* vg = vv + (long)b * SEQ * KVD + kvh * HDIM;
  const float scale = 0.08838834764831845f;   // 1/sqrt(128)

  for (int j = 0; j < nkt; ++j) {
    __syncthreads();                          // protect sKV from overwrite
#pragma unroll
    for (int cc = 0; cc < 4; ++cc) {          // K tile 64x128 (16KB) + V tile (16KB)
      int off = (cc * 4 + w) * 512 + l * 8;
      int row = off >> 7, col = off & 127;
      gload_lds16(kg + (long)(j * 64 + row) * KVD + col, &sKV[(cc * 4 + w) * 512]);
      gload_lds16(vg + (long)(j * 64 + row) * KVD + col, &sKV[8192 + (cc * 4 + w) * 512]);
    }
    __syncthreads();

    // S = Q K^T
    floatx4 sc[2][4] = {};
#pragma unroll
    for (int n = 0; n < 4; ++n) {
#pragma unroll
      for (int t = 0; t < 4; ++t) {
        bf16x8 kf = *(const bf16x8*)&sKV[(n * 16 + c) * 128 + t * 32 + g * 8];
        sc[0][n] = __builtin_amdgcn_mfma_f32_16x16x32_bf16(qf[0][t], kf, sc[0][n], 0, 0, 0);
        sc[1][n] = __builtin_amdgcn_mfma_f32_16x16x32_bf16(qf[1][t], kf, sc[1][n], 0, 0, 0);
      }
    }
    // scale + causal mask (mirrors reference: s*scale + (-1e9 above diag))
#pragma unroll
    for (int i = 0; i < 2; ++i)
#pragma unroll
      for (int r = 0; r < 4; ++r) {
        int srow = q0 + w * 32 + i * 16 + g * 4 + r;
#pragma unroll
        for (int n = 0; n < 4; ++n) {
          int scol = j * 64 + n * 16 + c;
          sc[i][n][r] = sc[i][n][r] * scale + ((scol > srow) ? -1e9f : 0.f);
        }
      }
    // online softmax (fp32), write P (bf16) to LDS
#pragma unroll
    for (int i = 0; i < 2; ++i)
#pragma unroll
      for (int r = 0; r < 4; ++r) {
        float mx = fmaxf(fmaxf(sc[i][0][r], sc[i][1][r]), fmaxf(sc[i][2][r], sc[i][3][r]));
        mx = fmaxf(mx, __shfl_xor(mx, 1));
        mx = fmaxf(mx, __shfl_xor(mx, 2));
        mx = fmaxf(mx, __shfl_xor(mx, 4));
        mx = fmaxf(mx, __shfl_xor(mx, 8));
        float mnew = fmaxf(mrow[i][r], mx);
        float alpha = __expf(mrow[i][r] - mnew);
        float rs = 0.f;
#pragma unroll
        for (int n = 0; n < 4; ++n) {
          float p = __expf(sc[i][n][r] - mnew);
          sc[i][n][r] = p;
          rs += p;
        }
        rs += __shfl_xor(rs, 1);
        rs += __shfl_xor(rs, 2);
        rs += __shfl_xor(rs, 4);
        rs += __shfl_xor(rs, 8);
        lrow[i][r] = lrow[i][r] * alpha + rs;
        mrow[i][r] = mnew;
#pragma unroll
        for (int d = 0; d < 8; ++d) oacc[i][d][r] *= alpha;
        int prow = w * 32 + i * 16 + g * 4 + r;
#pragma unroll
        for (int n = 0; n < 4; ++n)
          sP[prow * 64 + n * 16 + c] = f2bf(sc[i][n][r]);
      }
    // O += P V   (wave reads only its own sP rows -> no barrier needed; in-wave LDS order holds)
#pragma unroll
    for (int kt = 0; kt < 2; ++kt) {
      bf16x8 pf0 = *(const bf16x8*)&sP[(w * 32 + c) * 64 + kt * 32 + g * 8];
      bf16x8 pf1 = *(const bf16x8*)&sP[(w * 32 + 16 + c) * 64 + kt * 32 + g * 8];
#pragma unroll
      for (int d = 0; d < 8; ++d) {
        union { u16 h[8]; bf16x8 v; } vf;
#pragma unroll
        for (int jj = 0; jj < 8; ++jj)
          vf.h[jj] = sKV[8192 + (kt * 32 + g * 8 + jj) * 128 + d * 16 + c];
        oacc[0][d] = __builtin_amdgcn_mfma_f32_16x16x32_bf16(pf0, vf.v, oacc[0][d], 0, 0, 0);
        oacc[1][d] = __builtin_amdgcn_mfma_f32_16x16x32_bf16(pf1, vf.v, oacc[1][d], 0, 0, 0);
      }
    }
  }

  u16* ob = o + (long)(b * SEQ + q0) * DIMM + h * HDIM;
#pragma unroll
  for (int i = 0; i < 2; ++i)
#pragma unroll
    for (int r = 0; r < 4; ++r) {
      float inv = 1.f / lrow[i][r];
      int row = w * 32 + i * 16 + g * 4 + r;
#pragma unroll
      for (int d = 0; d < 8; ++d)
        ob[(long)row * DIMM + d * 16 + c] = f2bf(oacc[i][d][r] * inv);
    }
}

extern "C" void kernel_launch(void* const* d_in, const int* in_sizes, int n_in,
                              void* d_out, int out_size, void* d_ws, size_t ws_size,
                              hipStream_t stream) {
  (void)in_sizes; (void)n_in; (void)out_size; (void)ws_size;
  const float* x  = (const float*)d_in[0];
  const float* wq = (const float*)d_in[1];
  const float* wk = (const float*)d_in[2];
  const float* wv = (const float*)d_in[3];
  const float* wo = (const float*)d_in[4];
  const float* fc = (const float*)d_in[5];
  const float* fs = (const float*)d_in[6];
  // d_in[7]=mask (causal, applied analytically), d_in[8]=start_pos (0)

  // workspace layout (u16 elems), buffers reused via stream ordering: total ~160 MB
  u16* xb  = (u16*)d_ws;            // 16777216  x bf16
  u16* w16 = xb  + 16777216;        // 16777216  wq then wo
  u16* wkv = w16 + 16777216;        // 4194304   wk then wv
  u16* qb  = wkv + 4194304;         // 16777216  Q (post-rope)
  u16* kb  = qb  + 16777216;        // 4194304   K (post-rope)
  u16* vb  = kb  + 4194304;         // 4194304   V
  u16* ab  = vb  + 4194304;         // 16777216  attention output

  const int M = NB * SEQ;           // 4096

  cast_f2bf_kernel<<<16777216 / 2048, 256, 0, stream>>>(x,  xb,  16777216);
  cast_f2bf_kernel<<<16777216 / 2048, 256, 0, stream>>>(wq, w16, 16777216);
  gemm_nt<1><<<dim3(32, 32), 256, 0, stream>>>(xb, w16, qb, M, DIMM, DIMM, fc, fs);
  cast_f2bf_kernel<<<4194304 / 2048, 256, 0, stream>>>(wk, wkv, 4194304);
  gemm_nt<1><<<dim3(8, 32), 256, 0, stream>>>(xb, wkv, kb, M, KVD, DIMM, fc, fs);
  cast_f2bf_kernel<<<4194304 / 2048, 256, 0, stream>>>(wv, wkv, 4194304);
  gemm_nt<0><<<dim3(8, 32), 256, 0, stream>>>(xb, wkv, vb, M, KVD, DIMM, nullptr, nullptr);
  flash_attn<<<dim3(16, 64), 256, 0, stream>>>(qb, kb, vb, ab);
  cast_f2bf_kernel<<<16777216 / 2048, 256, 0, stream>>>(wo, w16, 16777216);
  gemm_nt<2><<<dim3(32, 32), 256, 0, stream>>>(ab, w16, d_out, M, DIMM, DIMM, nullptr, nullptr);
}

// Round 2
// 1045.674 us; speedup vs baseline: 1.2832x; 1.2832x over previous
//
#include <hip/hip_runtime.h>

// Attention_18605798326350: B=2,S=2048,DIM=4096,H=32,KVH=8,HD=128, rope theta 5e5, causal.
// R2: flash rebuilt in S^T orientation (q = lane&15 everywhere): in-lane softmax,
// conflict-free swizzled LDS (16B-chunk XOR row&7), V pre-transposed in global by the
// KV GEMM epilogue, PV as O^T = V^T * P^T. K+V projections merged into one GEMM.

#define HN   32
#define KVHN 8
#define HDIM 128
#define SEQ  2048
#define NB   2
#define DIMM 4096
#define KVD  1024

typedef __attribute__((ext_vector_type(4))) float floatx4;
typedef __attribute__((ext_vector_type(8))) short bf16x8;   // 8 bf16 (4 VGPRs)
typedef unsigned short u16;
typedef unsigned int   u32;

__device__ __forceinline__ u16 f2bf(float f) {           // RNE fp32->bf16
  union { float f; u32 u; } x; x.f = f;
  u32 r = x.u + 0x7fffu + ((x.u >> 16) & 1u);
  return (u16)(r >> 16);
}

// async global->LDS, 16B/lane; LDS dest = wave-uniform base + lane*16
__device__ __forceinline__ void gload_lds16(const u16* g, u16* l) {
  __builtin_amdgcn_global_load_lds(
      (const __attribute__((address_space(1))) void*)g,
      (__attribute__((address_space(3))) void*)l, 16, 0, 0);
}

__global__ __launch_bounds__(256) void cast_f2bf_kernel(const float* __restrict__ in,
                                                        u16* __restrict__ out, int n) {
  int i = (blockIdx.x * 256 + threadIdx.x) * 8;
  if (i + 8 > n) return;
  const float4* p = (const float4*)(in + i);
  float4 a = p[0], b = p[1];
  union { u16 h[8]; uint4 v; } r;
  r.h[0] = f2bf(a.x); r.h[1] = f2bf(a.y); r.h[2] = f2bf(a.z); r.h[3] = f2bf(a.w);
  r.h[4] = f2bf(b.x); r.h[5] = f2bf(b.y); r.h[6] = f2bf(b.z); r.h[7] = f2bf(b.w);
  *(uint4*)(out + i) = r.v;
}

// C[m,n] = sum_k A[m,k]*B[n,k].
// EPI 1: bf16 + fused RoPE -> Cv.   EPI 2: fp32 -> Cv.
// EPI 3: N=2048 combined KV: col<1024 -> RoPE+bf16 to Cv (K, row-major [M][1024]);
//        col>=1024 -> bf16 to Cv2 transposed V^T layout [b][col-1024][s] = [2][1024][2048].
template <int EPI>
__global__ __launch_bounds__(256) void gemm_nt(const u16* __restrict__ A, const u16* __restrict__ B,
                                               void* __restrict__ Cv, void* __restrict__ Cv2,
                                               int M, int N, int K,
                                               const float* __restrict__ fc, const float* __restrict__ fs) {
  __shared__ u16 lA[128 * 32];
  __shared__ u16 lB[128 * 32];
  const int tid = threadIdx.x;
  const int w = tid >> 6, l = tid & 63, g = (l >> 4) & 3, c = l & 15;
  const int m0 = blockIdx.y * 128, n0 = blockIdx.x * 128;
  const int wm = w & 1, wn = w >> 1;
  floatx4 acc[4][4] = {};
  const u16* Ab = A + (long)m0 * K;
  const u16* Bb = B + (long)n0 * K;
  const int off0 = w * 512 + l * 8;
  const int r0 = off0 >> 5, c0 = off0 & 31;
  const int off1 = off0 + 2048;
  const int r1 = off1 >> 5, c1 = off1 & 31;

  for (int kt = 0; kt < K; kt += 32) {
    __syncthreads();
    gload_lds16(Ab + (long)r0 * K + kt + c0, &lA[w * 512]);
    gload_lds16(Bb + (long)r0 * K + kt + c0, &lB[w * 512]);
    gload_lds16(Ab + (long)r1 * K + kt + c1, &lA[2048 + w * 512]);
    gload_lds16(Bb + (long)r1 * K + kt + c1, &lB[2048 + w * 512]);
    __syncthreads();
    bf16x8 af[4], bf[4];
#pragma unroll
    for (int i = 0; i < 4; ++i) af[i] = *(const bf16x8*)&lA[(wm * 64 + i * 16 + c) * 32 + g * 8];
#pragma unroll
    for (int j = 0; j < 4; ++j) bf[j] = *(const bf16x8*)&lB[(wn * 64 + j * 16 + c) * 32 + g * 8];
#pragma unroll
    for (int i = 0; i < 4; ++i)
#pragma unroll
      for (int j = 0; j < 4; ++j)
        acc[i][j] = __builtin_amdgcn_mfma_f32_16x16x32_bf16(af[i], bf[j], acc[i][j], 0, 0, 0);
  }

#pragma unroll
  for (int i = 0; i < 4; ++i)
#pragma unroll
    for (int j = 0; j < 4; ++j) {
      const int colb = n0 + wn * 64 + j * 16;
      const int col = colb + c;
      const int rowb = m0 + wm * 64 + i * 16 + g * 4;
      if (EPI == 3 && colb >= 1024) {
        // V half: store V^T[b][d=col-1024][s] packed 4 consecutive s (r=0..3)
        const int bb = rowb >> 11, s0 = rowb & (SEQ - 1);
        union { u16 h4[4]; uint2 v; } pk;
#pragma unroll
        for (int r = 0; r < 4; ++r) pk.h4[r] = f2bf(acc[i][j][r]);
        *(uint2*)((u16*)Cv2 + ((long)(bb * 1024 + (col - 1024))) * SEQ + s0) = pk.v;
      } else {
#pragma unroll
        for (int r = 0; r < 4; ++r) {
          const int row = rowb + r;
          float v = acc[i][j][r];
          if (EPI == 1 || EPI == 3) {
            // interleaved RoPE, partner = lane^1 (adjacent col)
            float pv = __shfl_xor(v, 1);
            int pos = row & (SEQ - 1);
            int fi = (col & (HDIM - 1)) >> 1;
            float cs = fc[pos * (HDIM / 2) + fi];
            float sn = fs[pos * (HDIM / 2) + fi];
            v = (col & 1) ? (pv * sn + v * cs) : (v * cs - pv * sn);
          }
          if (EPI == 2)      ((float*)Cv)[(long)row * N + col] = v;
          else if (EPI == 3) ((u16*)Cv)[(long)row * KVD + col] = f2bf(v);
          else               ((u16*)Cv)[(long)row * N + col] = f2bf(v);
        }
      }
    }
}

// Flash attention, S^T orientation. grid(16, B*H). BQ=128 (4 waves x 32 q), BK=64.
// LDS: smem[0,16384): sQ 128x128 (preload phase) then sK 64x128 [0,8192) + sVT 128x64 [8192,16384).
//      smem[16384,24576): per-wave P tile 32x64.  All tiles XOR-swizzled: 16B chunk k -> k^(row&7).
__global__ __launch_bounds__(256) void flash_attn(const u16* __restrict__ q, const u16* __restrict__ kk,
                                                  const u16* __restrict__ vt, u16* __restrict__ o) {
  __shared__ u16 smem[24576];
  const int tid = threadIdx.x;
  const int w = tid >> 6, l = tid & 63, g = (l >> 4) & 3, c = l & 15;
  const int bh = blockIdx.y, b = bh >> 5, h = bh & 31, kvh = h >> 2;
  const int q0 = (15 - blockIdx.x) * 128;          // heavy (causal) blocks first

  const u16* qg = q  + (long)(b * SEQ + q0) * DIMM + h * HDIM;
  const u16* kg = kk + (long)b * SEQ * KVD + kvh * HDIM;
  const u16* vg = vt + (long)(b * KVD + kvh * HDIM) * SEQ;   // V^T rows d, stride SEQ

  { // stage Q 128x128, swizzled
    const int rin = l >> 4, kap = l & 15;
#pragma unroll
    for (int cc = 0; cc < 8; ++cc) {
      int row = cc * 16 + w * 4 + rin;
      gload_lds16(qg + (long)row * DIMM + ((kap ^ (row & 7)) * 8), &smem[(cc * 16 + w * 4) * 128]);
    }
  }
  __syncthreads();
  bf16x8 qf[2][4];                                  // B-operand fragments: Q[q=c][dim]
#pragma unroll
  for (int nq = 0; nq < 2; ++nq)
#pragma unroll
    for (int t = 0; t < 4; ++t)
      qf[nq][t] = *(const bf16x8*)&smem[(w * 32 + nq * 16 + c) * 128 + ((t * 4 + g) ^ (c & 7)) * 8];

  u16* sP = &smem[16384 + w * 2048];                // per-wave 32x64 P tile
  floatx4 oacc[8][2] = {};                          // O^T frags: [d-tile][q-tile]
  float mrow[2] = {-3e38f, -3e38f}, lrow[2] = {0.f, 0.f};
  const float scale = 0.08838834764831845f;         // 1/sqrt(128)
  const int nkt = (q0 + 128) >> 6;
  const int qwave = q0 + w * 32;

  for (int j = 0; j < nkt; ++j) {
    __syncthreads();
    { // stage K 64x128 + V^T 128x64, swizzled
      const int r4 = l >> 4, ka16 = l & 15, r8 = l >> 3, ka8 = l & 7;
#pragma unroll
      for (int cc = 0; cc < 4; ++cc) {
        int srow = cc * 16 + w * 4 + r4;
        gload_lds16(kg + (long)(j * 64 + srow) * KVD + ((ka16 ^ (srow & 7)) * 8),
                    &smem[(cc * 16 + w * 4) * 128]);
      }
#pragma unroll
      for (int cc = 0; cc < 4; ++cc) {
        int drow = cc * 32 + w * 8 + r8;
        gload_lds16(vg + (long)drow * SEQ + j * 64 + ((ka8 ^ (drow & 7)) * 8),
                    &smem[8192 + (cc * 32 + w * 8) * 64]);
      }
    }
    __syncthreads();
    if (j * 64 > qwave + 31) continue;              // tile fully masked for this wave

    // St = K * Q^T : St frag rows = s (g*4+r), cols = q (c)
    floatx4 sc[4][2] = {};
#pragma unroll
    for (int ms = 0; ms < 4; ++ms) {
      bf16x8 kf[4];
#pragma unroll
      for (int t = 0; t < 4; ++t)
        kf[t] = *(const bf16x8*)&smem[(ms * 16 + c) * 128 + ((t * 4 + g) ^ (c & 7)) * 8];
#pragma unroll
      for (int t = 0; t < 4; ++t) {
        sc[ms][0] = __builtin_amdgcn_mfma_f32_16x16x32_bf16(kf[t], qf[0][t], sc[ms][0], 0, 0, 0);
        sc[ms][1] = __builtin_amdgcn_mfma_f32_16x16x32_bf16(kf[t], qf[1][t], sc[ms][1], 0, 0, 0);
      }
    }

    const bool needMask = (j * 64 + 63) > qwave;    // wave-uniform
#pragma unroll
    for (int nq = 0; nq < 2; ++nq) {
      const int qv = qwave + nq * 16 + c;
      float mx = -3e38f;
#pragma unroll
      for (int ms = 0; ms < 4; ++ms) {
        const int sbase = j * 64 + ms * 16 + g * 4;
#pragma unroll
        for (int r = 0; r < 4; ++r) {
          float v = sc[ms][nq][r] * scale;
          if (needMask && (sbase + r > qv)) v = -1e9f;
          sc[ms][nq][r] = v;
          mx = fmaxf(mx, v);
        }
      }
      mx = fmaxf(mx, __shfl_xor(mx, 16));
      mx = fmaxf(mx, __shfl_xor(mx, 32));
      const float mnew = fmaxf(mrow[nq], mx);
      const float alpha = __expf(mrow[nq] - mnew);
      mrow[nq] = mnew;
      float rs = 0.f;
#pragma unroll
      for (int ms = 0; ms < 4; ++ms)
#pragma unroll
        for (int r = 0; r < 4; ++r) {
          float p = __expf(sc[ms][nq][r] - mnew);
          sc[ms][nq][r] = p;
          rs += p;
        }
      rs += __shfl_xor(rs, 16);
      rs += __shfl_xor(rs, 32);
      lrow[nq] = lrow[nq] * alpha + rs;
#pragma unroll
      for (int md = 0; md < 8; ++md) oacc[md][nq] *= alpha;
      // pack P row chunk: s = ms*16 + g*4 + r lands at chunk (ms*2+(g>>1)) half (g&1)
#pragma unroll
      for (int ms = 0; ms < 4; ++ms) {
        u32 lo = (u32)f2bf(sc[ms][nq][0]) | ((u32)f2bf(sc[ms][nq][1]) << 16);
        u32 hi = (u32)f2bf(sc[ms][nq][2]) | ((u32)f2bf(sc[ms][nq][3]) << 16);
        uint2 val; val.x = lo; val.y = hi;
        const int sc16 = ms * 2 + (g >> 1);
        *(uint2*)&sP[(nq * 16 + c) * 64 + ((sc16 ^ (c & 7)) * 8) + (g & 1) * 4] = val;
      }
    }

    // O^T += V^T * P^T
    bf16x8 pf[2][2];
#pragma unroll
    for (int kb2 = 0; kb2 < 2; ++kb2)
#pragma unroll
      for (int nq = 0; nq < 2; ++nq)
        pf[kb2][nq] = *(const bf16x8*)&sP[(nq * 16 + c) * 64 + (((kb2 * 4 + g) ^ (c & 7)) * 8)];
#pragma unroll
    for (int md = 0; md < 8; ++md)
#pragma unroll
      for (int kb2 = 0; kb2 < 2; ++kb2) {
        bf16x8 vf = *(const bf16x8*)&smem[8192 + (md * 16 + c) * 64 + (((kb2 * 4 + g) ^ (c & 7)) * 8)];
        oacc[md][0] = __builtin_amdgcn_mfma_f32_16x16x32_bf16(vf, pf[kb2][0], oacc[md][0], 0, 0, 0);
        oacc[md][1] = __builtin_amdgcn_mfma_f32_16x16x32_bf16(vf, pf[kb2][1], oacc[md][1], 0, 0, 0);
      }
  }

  // epilogue: O^T frag -> O row-major; lane holds 4 consecutive d (r), q = c
  u16* ob = o + (long)(b * SEQ + q0 + w * 32) * DIMM + h * HDIM;
#pragma unroll
  for (int nq = 0; nq < 2; ++nq) {
    const float inv = 1.f / lrow[nq];
#pragma unroll
    for (int md = 0; md < 8; ++md) {
      union { u16 h4[4]; uint2 v; } pk;
#pragma unroll
      for (int r = 0; r < 4; ++r) pk.h4[r] = f2bf(oacc[md][nq][r] * inv);
      *(uint2*)&ob[(long)(nq * 16 + c) * DIMM + md * 16 + g * 4] = pk.v;
    }
  }
}

extern "C" void kernel_launch(void* const* d_in, const int* in_sizes, int n_in,
                              void* d_out, int out_size, void* d_ws, size_t ws_size,
                              hipStream_t stream) {
  (void)in_sizes; (void)n_in; (void)out_size; (void)ws_size;
  const float* x  = (const float*)d_in[0];
  const float* wq = (const float*)d_in[1];
  const float* wk = (const float*)d_in[2];
  const float* wv = (const float*)d_in[3];
  const float* wo = (const float*)d_in[4];
  const float* fc = (const float*)d_in[5];
  const float* fs = (const float*)d_in[6];

  // workspace (u16 elems), 151 MB total; w16 reused for wq -> wk|wv -> wo (stream-ordered)
  u16* xb  = (u16*)d_ws;            // 16777216
  u16* w16 = xb  + 16777216;        // 16777216
  u16* qb  = w16 + 16777216;        // 16777216
  u16* kb  = qb  + 16777216;        //  4194304
  u16* vT  = kb  + 4194304;         //  4194304  V^T [2][1024][2048]
  u16* ab  = vT  + 4194304;         // 16777216

  const int M = NB * SEQ;           // 4096

  cast_f2bf_kernel<<<16777216 / 2048, 256, 0, stream>>>(x,  xb,  16777216);
  cast_f2bf_kernel<<<16777216 / 2048, 256, 0, stream>>>(wq, w16, 16777216);
  gemm_nt<1><<<dim3(32, 32), 256, 0, stream>>>(xb, w16, qb, nullptr, M, DIMM, DIMM, fc, fs);
  cast_f2bf_kernel<<<4194304 / 2048, 256, 0, stream>>>(wk, w16, 4194304);
  cast_f2bf_kernel<<<4194304 / 2048, 256, 0, stream>>>(wv, w16 + 4194304, 4194304);
  gemm_nt<3><<<dim3(16, 32), 256, 0, stream>>>(xb, w16, kb, vT, M, 2048, DIMM, fc, fs);
  flash_attn<<<dim3(16, 64), 256, 0, stream>>>(qb, kb, vT, ab);
  cast_f2bf_kernel<<<16777216 / 2048, 256, 0, stream>>>(wo, w16, 16777216);
  gemm_nt<2><<<dim3(32, 32), 256, 0, stream>>>(ab, w16, d_out, nullptr, M, DIMM, DIMM, nullptr, nullptr);
}

// Round 3
// 1044.077 us; speedup vs baseline: 1.2852x; 1.0015x over previous
//
#include <hip/hip_runtime.h>

// Attention_18605798326350: B=2,S=2048,DIM=4096,H=32,KVH=8,HD=128, rope theta 5e5, causal.
// R3: flash K-loop split-phase pipeline — K(j+1) staged during softmax/PV(j), V(j+1) staged
// during QK(j+1); every barrier's vmcnt(0) drain now fires on loads issued a compute-phase
// earlier. Same LDS (48KB, 3 blocks/CU), same 2 barriers/tile. GEMMs unchanged from R2.

#define HN   32
#define KVHN 8
#define HDIM 128
#define SEQ  2048
#define NB   2
#define DIMM 4096
#define KVD  1024

typedef __attribute__((ext_vector_type(4))) float floatx4;
typedef __attribute__((ext_vector_type(8))) short bf16x8;   // 8 bf16 (4 VGPRs)
typedef unsigned short u16;
typedef unsigned int   u32;

__device__ __forceinline__ u16 f2bf(float f) {           // RNE fp32->bf16
  union { float f; u32 u; } x; x.f = f;
  u32 r = x.u + 0x7fffu + ((x.u >> 16) & 1u);
  return (u16)(r >> 16);
}

// async global->LDS, 16B/lane; LDS dest = wave-uniform base + lane*16
__device__ __forceinline__ void gload_lds16(const u16* g, u16* l) {
  __builtin_amdgcn_global_load_lds(
      (const __attribute__((address_space(1))) void*)g,
      (__attribute__((address_space(3))) void*)l, 16, 0, 0);
}

__global__ __launch_bounds__(256) void cast_f2bf_kernel(const float* __restrict__ in,
                                                        u16* __restrict__ out, int n) {
  int i = (blockIdx.x * 256 + threadIdx.x) * 8;
  if (i + 8 > n) return;
  const float4* p = (const float4*)(in + i);
  float4 a = p[0], b = p[1];
  union { u16 h[8]; uint4 v; } r;
  r.h[0] = f2bf(a.x); r.h[1] = f2bf(a.y); r.h[2] = f2bf(a.z); r.h[3] = f2bf(a.w);
  r.h[4] = f2bf(b.x); r.h[5] = f2bf(b.y); r.h[6] = f2bf(b.z); r.h[7] = f2bf(b.w);
  *(uint4*)(out + i) = r.v;
}

// C[m,n] = sum_k A[m,k]*B[n,k].
// EPI 1: bf16 + fused RoPE -> Cv.   EPI 2: fp32 -> Cv.
// EPI 3: N=2048 combined KV: col<1024 -> RoPE+bf16 to Cv (K row-major [M][1024]);
//        col>=1024 -> bf16 to Cv2 as V^T [b][d][s] = [2][1024][2048].
template <int EPI>
__global__ __launch_bounds__(256) void gemm_nt(const u16* __restrict__ A, const u16* __restrict__ B,
                                               void* __restrict__ Cv, void* __restrict__ Cv2,
                                               int M, int N, int K,
                                               const float* __restrict__ fc, const float* __restrict__ fs) {
  __shared__ u16 lA[128 * 32];
  __shared__ u16 lB[128 * 32];
  const int tid = threadIdx.x;
  const int w = tid >> 6, l = tid & 63, g = (l >> 4) & 3, c = l & 15;
  const int m0 = blockIdx.y * 128, n0 = blockIdx.x * 128;
  const int wm = w & 1, wn = w >> 1;
  floatx4 acc[4][4] = {};
  const u16* Ab = A + (long)m0 * K;
  const u16* Bb = B + (long)n0 * K;
  const int off0 = w * 512 + l * 8;
  const int r0 = off0 >> 5, c0 = off0 & 31;
  const int off1 = off0 + 2048;
  const int r1 = off1 >> 5, c1 = off1 & 31;

  for (int kt = 0; kt < K; kt += 32) {
    __syncthreads();
    gload_lds16(Ab + (long)r0 * K + kt + c0, &lA[w * 512]);
    gload_lds16(Bb + (long)r0 * K + kt + c0, &lB[w * 512]);
    gload_lds16(Ab + (long)r1 * K + kt + c1, &lA[2048 + w * 512]);
    gload_lds16(Bb + (long)r1 * K + kt + c1, &lB[2048 + w * 512]);
    __syncthreads();
    bf16x8 af[4], bf[4];
#pragma unroll
    for (int i = 0; i < 4; ++i) af[i] = *(const bf16x8*)&lA[(wm * 64 + i * 16 + c) * 32 + g * 8];
#pragma unroll
    for (int j = 0; j < 4; ++j) bf[j] = *(const bf16x8*)&lB[(wn * 64 + j * 16 + c) * 32 + g * 8];
#pragma unroll
    for (int i = 0; i < 4; ++i)
#pragma unroll
      for (int j = 0; j < 4; ++j)
        acc[i][j] = __builtin_amdgcn_mfma_f32_16x16x32_bf16(af[i], bf[j], acc[i][j], 0, 0, 0);
  }

#pragma unroll
  for (int i = 0; i < 4; ++i)
#pragma unroll
    for (int j = 0; j < 4; ++j) {
      const int colb = n0 + wn * 64 + j * 16;
      const int col = colb + c;
      const int rowb = m0 + wm * 64 + i * 16 + g * 4;
      if (EPI == 3 && colb >= 1024) {
        const int bb = rowb >> 11, s0 = rowb & (SEQ - 1);
        union { u16 h4[4]; uint2 v; } pk;
#pragma unroll
        for (int r = 0; r < 4; ++r) pk.h4[r] = f2bf(acc[i][j][r]);
        *(uint2*)((u16*)Cv2 + ((long)(bb * 1024 + (col - 1024))) * SEQ + s0) = pk.v;
      } else {
#pragma unroll
        for (int r = 0; r < 4; ++r) {
          const int row = rowb + r;
          float v = acc[i][j][r];
          if (EPI == 1 || EPI == 3) {
            float pv = __shfl_xor(v, 1);
            int pos = row & (SEQ - 1);
            int fi = (col & (HDIM - 1)) >> 1;
            float cs = fc[pos * (HDIM / 2) + fi];
            float sn = fs[pos * (HDIM / 2) + fi];
            v = (col & 1) ? (pv * sn + v * cs) : (v * cs - pv * sn);
          }
          if (EPI == 2)      ((float*)Cv)[(long)row * N + col] = v;
          else if (EPI == 3) ((u16*)Cv)[(long)row * KVD + col] = f2bf(v);
          else               ((u16*)Cv)[(long)row * N + col] = f2bf(v);
        }
      }
    }
}

// Flash attention, S^T orientation, split-phase pipeline. grid(16, B*H). BQ=128, BK=64.
// LDS: sK 64x128 [0,8192) | sVT 128x64 [8192,16384) | per-wave P 32x64 [16384,24576).
// Swizzle: 16B chunk k -> k^(row&7) (applied at staging source).
// Pipeline per tile j:  QK(j) | sync1 | stageK(j+1) | softmax+PV(j) | sync2 | stageV(j+1).
// sync1 drains V(j) (issued a QK-phase earlier); sync2 drains K(j+1) (issued a PV-phase earlier).
__global__ __launch_bounds__(256) void flash_attn(const u16* __restrict__ q, const u16* __restrict__ kk,
                                                  const u16* __restrict__ vt, u16* __restrict__ o) {
  __shared__ u16 smem[24576];
  const int tid = threadIdx.x;
  const int w = tid >> 6, l = tid & 63, g = (l >> 4) & 3, c = l & 15;
  const int bh = blockIdx.y, b = bh >> 5, h = bh & 31, kvh = h >> 2;
  const int q0 = (15 - blockIdx.x) * 128;          // heavy (causal) blocks first

  const u16* qg = q  + (long)(b * SEQ + q0) * DIMM + h * HDIM;
  const u16* kg = kk + (long)b * SEQ * KVD + kvh * HDIM;
  const u16* vg = vt + (long)(b * KVD + kvh * HDIM) * SEQ;   // V^T rows d, stride SEQ

  const int r4 = l >> 4, ka16 = l & 15, r8 = l >> 3, ka8 = l & 7;

  { // stage Q 128x128 swizzled into [0,32KB)
#pragma unroll
    for (int cc = 0; cc < 8; ++cc) {
      int row = cc * 16 + w * 4 + r4;
      gload_lds16(qg + (long)row * DIMM + ((ka16 ^ (row & 7)) * 8), &smem[(cc * 16 + w * 4) * 128]);
    }
  }
  __syncthreads();
  bf16x8 qf[2][4];                                  // B-operand frags: Q[q=c][dim]
#pragma unroll
  for (int nq = 0; nq < 2; ++nq)
#pragma unroll
    for (int t = 0; t < 4; ++t)
      qf[nq][t] = *(const bf16x8*)&smem[(w * 32 + nq * 16 + c) * 128 + ((t * 4 + g) ^ (c & 7)) * 8];
  __syncthreads();                                  // qf reads done before K0/V0 overwrite

  u16* sP = &smem[16384 + w * 2048];
  floatx4 oacc[8][2] = {};
  float mrow[2] = {-3e38f, -3e38f}, lrow[2] = {0.f, 0.f};
  const float scale = 0.08838834764831845f;
  const int nkt = (q0 + 128) >> 6;
  const int qwave = q0 + w * 32;

  // prologue: stage K(0), V(0)
#pragma unroll
  for (int cc = 0; cc < 4; ++cc) {
    int srow = cc * 16 + w * 4 + r4;
    gload_lds16(kg + (long)srow * KVD + ((ka16 ^ (srow & 7)) * 8), &smem[(cc * 16 + w * 4) * 128]);
  }
#pragma unroll
  for (int cc = 0; cc < 4; ++cc) {
    int drow = cc * 32 + w * 8 + r8;
    gload_lds16(vg + (long)drow * SEQ + ((ka8 ^ (drow & 7)) * 8), &smem[8192 + (cc * 32 + w * 8) * 64]);
  }
  __syncthreads();                                  // drain K0,V0

  for (int j = 0; j < nkt; ++j) {
    const bool active = (j * 64 <= qwave + 31);     // wave-uniform
    floatx4 sc[4][2] = {};
    if (active) {                                   // St = K * Q^T
#pragma unroll
      for (int ms = 0; ms < 4; ++ms) {
        bf16x8 kf[4];
#pragma unroll
        for (int t = 0; t < 4; ++t)
          kf[t] = *(const bf16x8*)&smem[(ms * 16 + c) * 128 + ((t * 4 + g) ^ (c & 7)) * 8];
#pragma unroll
        for (int t = 0; t < 4; ++t) {
          sc[ms][0] = __builtin_amdgcn_mfma_f32_16x16x32_bf16(kf[t], qf[0][t], sc[ms][0], 0, 0, 0);
          sc[ms][1] = __builtin_amdgcn_mfma_f32_16x16x32_bf16(kf[t], qf[1][t], sc[ms][1], 0, 0, 0);
        }
      }
    }
    __syncthreads();                                // Kbuf free; drains V(j)

    if (j + 1 < nkt) {                              // stage K(j+1) — drains at sync2
#pragma unroll
      for (int cc = 0; cc < 4; ++cc) {
        int srow = cc * 16 + w * 4 + r4;
        gload_lds16(kg + (long)((j + 1) * 64 + srow) * KVD + ((ka16 ^ (srow & 7)) * 8),
                    &smem[(cc * 16 + w * 4) * 128]);
      }
    }

    if (active) {
      const bool needMask = (j * 64 + 63) > qwave;  // wave-uniform
#pragma unroll
      for (int nq = 0; nq < 2; ++nq) {
        const int qv = qwave + nq * 16 + c;
        float mx = -3e38f;
#pragma unroll
        for (int ms = 0; ms < 4; ++ms) {
          const int sbase = j * 64 + ms * 16 + g * 4;
#pragma unroll
          for (int r = 0; r < 4; ++r) {
            float v = sc[ms][nq][r] * scale;
            if (needMask && (sbase + r > qv)) v = -1e9f;
            sc[ms][nq][r] = v;
            mx = fmaxf(mx, v);
          }
        }
        mx = fmaxf(mx, __shfl_xor(mx, 16));
        mx = fmaxf(mx, __shfl_xor(mx, 32));
        const float mnew = fmaxf(mrow[nq], mx);
        const float alpha = __expf(mrow[nq] - mnew);
        mrow[nq] = mnew;
        float rs = 0.f;
#pragma unroll
        for (int ms = 0; ms < 4; ++ms)
#pragma unroll
          for (int r = 0; r < 4; ++r) {
            float p = __expf(sc[ms][nq][r] - mnew);
            sc[ms][nq][r] = p;
            rs += p;
          }
        rs += __shfl_xor(rs, 16);
        rs += __shfl_xor(rs, 32);
        lrow[nq] = lrow[nq] * alpha + rs;
#pragma unroll
        for (int md = 0; md < 8; ++md) oacc[md][nq] *= alpha;
#pragma unroll
        for (int ms = 0; ms < 4; ++ms) {            // pack P (bf16) to per-wave LDS tile
          u32 lo = (u32)f2bf(sc[ms][nq][0]) | ((u32)f2bf(sc[ms][nq][1]) << 16);
          u32 hi = (u32)f2bf(sc[ms][nq][2]) | ((u32)f2bf(sc[ms][nq][3]) << 16);
          uint2 val; val.x = lo; val.y = hi;
          const int sc16 = ms * 2 + (g >> 1);
          *(uint2*)&sP[(nq * 16 + c) * 64 + ((sc16 ^ (c & 7)) * 8) + (g & 1) * 4] = val;
        }
      }

      // O^T += V^T * P^T   (reads V(j): drained at sync1; P: same-wave LDS order)
      bf16x8 pf[2][2];
#pragma unroll
      for (int kb2 = 0; kb2 < 2; ++kb2)
#pragma unroll
        for (int nq = 0; nq < 2; ++nq)
          pf[kb2][nq] = *(const bf16x8*)&sP[(nq * 16 + c) * 64 + (((kb2 * 4 + g) ^ (c & 7)) * 8)];
#pragma unroll
      for (int md = 0; md < 8; ++md)
#pragma unroll
        for (int kb2 = 0; kb2 < 2; ++kb2) {
          bf16x8 vf = *(const bf16x8*)&smem[8192 + (md * 16 + c) * 64 + (((kb2 * 4 + g) ^ (c & 7)) * 8)];
          oacc[md][0] = __builtin_amdgcn_mfma_f32_16x16x32_bf16(vf, pf[kb2][0], oacc[md][0], 0, 0, 0);
          oacc[md][1] = __builtin_amdgcn_mfma_f32_16x16x32_bf16(vf, pf[kb2][1], oacc[md][1], 0, 0, 0);
        }
    }
    __syncthreads();                                // Vbuf free; drains K(j+1)

    if (j + 1 < nkt) {                              // stage V(j+1) — drains at next sync1
#pragma unroll
      for (int cc = 0; cc < 4; ++cc) {
        int drow = cc * 32 + w * 8 + r8;
        gload_lds16(vg + (long)drow * SEQ + (j + 1) * 64 + ((ka8 ^ (drow & 7)) * 8),
                    &smem[8192 + (cc * 32 + w * 8) * 64]);
      }
    }
  }

  // epilogue: O^T frag -> O row-major; lane holds 4 consecutive d (r), q = c
  u16* ob = o + (long)(b * SEQ + q0 + w * 32) * DIMM + h * HDIM;
#pragma unroll
  for (int nq = 0; nq < 2; ++nq) {
    const float inv = 1.f / lrow[nq];
#pragma unroll
    for (int md = 0; md < 8; ++md) {
      union { u16 h4[4]; uint2 v; } pk;
#pragma unroll
      for (int r = 0; r < 4; ++r) pk.h4[r] = f2bf(oacc[md][nq][r] * inv);
      *(uint2*)&ob[(long)(nq * 16 + c) * DIMM + md * 16 + g * 4] = pk.v;
    }
  }
}

extern "C" void kernel_launch(void* const* d_in, const int* in_sizes, int n_in,
                              void* d_out, int out_size, void* d_ws, size_t ws_size,
                              hipStream_t stream) {
  (void)in_sizes; (void)n_in; (void)out_size; (void)ws_size;
  const float* x  = (const float*)d_in[0];
  const float* wq = (const float*)d_in[1];
  const float* wk = (const float*)d_in[2];
  const float* wv = (const float*)d_in[3];
  const float* wo = (const float*)d_in[4];
  const float* fc = (const float*)d_in[5];
  const float* fs = (const float*)d_in[6];

  u16* xb  = (u16*)d_ws;            // 16777216
  u16* w16 = xb  + 16777216;        // 16777216
  u16* qb  = w16 + 16777216;        // 16777216
  u16* kb  = qb  + 16777216;        //  4194304
  u16* vT  = kb  + 4194304;         //  4194304  V^T [2][1024][2048]
  u16* ab  = vT  + 4194304;         // 16777216

  const int M = NB * SEQ;           // 4096

  cast_f2bf_kernel<<<16777216 / 2048, 256, 0, stream>>>(x,  xb,  16777216);
  cast_f2bf_kernel<<<16777216 / 2048, 256, 0, stream>>>(wq, w16, 16777216);
  gemm_nt<1><<<dim3(32, 32), 256, 0, stream>>>(xb, w16, qb, nullptr, M, DIMM, DIMM, fc, fs);
  cast_f2bf_kernel<<<4194304 / 2048, 256, 0, stream>>>(wk, w16, 4194304);
  cast_f2bf_kernel<<<4194304 / 2048, 256, 0, stream>>>(wv, w16 + 4194304, 4194304);
  gemm_nt<3><<<dim3(16, 32), 256, 0, stream>>>(xb, w16, kb, vT, M, 2048, DIMM, fc, fs);
  flash_attn<<<dim3(16, 64), 256, 0, stream>>>(qb, kb, vT, ab);
  cast_f2bf_kernel<<<16777216 / 2048, 256, 0, stream>>>(wo, w16, 16777216);
  gemm_nt<2><<<dim3(32, 32), 256, 0, stream>>>(ab, w16, d_out, nullptr, M, DIMM, DIMM, nullptr, nullptr);
}

// Round 4
// 933.015 us; speedup vs baseline: 1.4381x; 1.1190x over previous
//
#include <hip/hip_runtime.h>

// Attention_18605798326350: B=2,S=2048,DIM=4096,H=32,KVH=8,HD=128, rope theta 5e5, causal.
// R4: flash occupancy attack — BQ=64 (4 waves x 16 q-rows), grid 2048 blocks, LDS 40KB
// (4 blocks/CU), __launch_bounds__(256,4) => 16 waves/CU (was ~2 avg). 1/sqrt(HD) folded
// into Q-projection epilogue. Split-phase K/V staging kept. GEMMs otherwise unchanged.

#define HN   32
#define KVHN 8
#define HDIM 128
#define SEQ  2048
#define NB   2
#define DIMM 4096
#define KVD  1024

typedef __attribute__((ext_vector_type(4))) float floatx4;
typedef __attribute__((ext_vector_type(8))) short bf16x8;   // 8 bf16 (4 VGPRs)
typedef unsigned short u16;
typedef unsigned int   u32;

__device__ __forceinline__ u16 f2bf(float f) {           // RNE fp32->bf16
  union { float f; u32 u; } x; x.f = f;
  u32 r = x.u + 0x7fffu + ((x.u >> 16) & 1u);
  return (u16)(r >> 16);
}

// async global->LDS, 16B/lane; LDS dest = wave-uniform base + lane*16
__device__ __forceinline__ void gload_lds16(const u16* g, u16* l) {
  __builtin_amdgcn_global_load_lds(
      (const __attribute__((address_space(1))) void*)g,
      (__attribute__((address_space(3))) void*)l, 16, 0, 0);
}

__global__ __launch_bounds__(256) void cast_f2bf_kernel(const float* __restrict__ in,
                                                        u16* __restrict__ out, int n) {
  int i = (blockIdx.x * 256 + threadIdx.x) * 8;
  if (i + 8 > n) return;
  const float4* p = (const float4*)(in + i);
  float4 a = p[0], b = p[1];
  union { u16 h[8]; uint4 v; } r;
  r.h[0] = f2bf(a.x); r.h[1] = f2bf(a.y); r.h[2] = f2bf(a.z); r.h[3] = f2bf(a.w);
  r.h[4] = f2bf(b.x); r.h[5] = f2bf(b.y); r.h[6] = f2bf(b.z); r.h[7] = f2bf(b.w);
  *(uint4*)(out + i) = r.v;
}

// C[m,n] = sum_k A[m,k]*B[n,k].
// EPI 1: bf16 + RoPE + 1/sqrt(HD) scale -> Cv (Q).   EPI 2: fp32 -> Cv.
// EPI 3: N=2048 combined KV: col<1024 -> RoPE+bf16 to Cv (K row-major [M][1024]);
//        col>=1024 -> bf16 to Cv2 as V^T [b][d][s] = [2][1024][2048].
template <int EPI>
__global__ __launch_bounds__(256) void gemm_nt(const u16* __restrict__ A, const u16* __restrict__ B,
                                               void* __restrict__ Cv, void* __restrict__ Cv2,
                                               int M, int N, int K,
                                               const float* __restrict__ fc, const float* __restrict__ fs) {
  __shared__ u16 lA[128 * 32];
  __shared__ u16 lB[128 * 32];
  const int tid = threadIdx.x;
  const int w = tid >> 6, l = tid & 63, g = (l >> 4) & 3, c = l & 15;
  const int m0 = blockIdx.y * 128, n0 = blockIdx.x * 128;
  const int wm = w & 1, wn = w >> 1;
  floatx4 acc[4][4] = {};
  const u16* Ab = A + (long)m0 * K;
  const u16* Bb = B + (long)n0 * K;
  const int off0 = w * 512 + l * 8;
  const int r0 = off0 >> 5, c0 = off0 & 31;
  const int off1 = off0 + 2048;
  const int r1 = off1 >> 5, c1 = off1 & 31;

  for (int kt = 0; kt < K; kt += 32) {
    __syncthreads();
    gload_lds16(Ab + (long)r0 * K + kt + c0, &lA[w * 512]);
    gload_lds16(Bb + (long)r0 * K + kt + c0, &lB[w * 512]);
    gload_lds16(Ab + (long)r1 * K + kt + c1, &lA[2048 + w * 512]);
    gload_lds16(Bb + (long)r1 * K + kt + c1, &lB[2048 + w * 512]);
    __syncthreads();
    bf16x8 af[4], bf[4];
#pragma unroll
    for (int i = 0; i < 4; ++i) af[i] = *(const bf16x8*)&lA[(wm * 64 + i * 16 + c) * 32 + g * 8];
#pragma unroll
    for (int j = 0; j < 4; ++j) bf[j] = *(const bf16x8*)&lB[(wn * 64 + j * 16 + c) * 32 + g * 8];
#pragma unroll
    for (int i = 0; i < 4; ++i)
#pragma unroll
      for (int j = 0; j < 4; ++j)
        acc[i][j] = __builtin_amdgcn_mfma_f32_16x16x32_bf16(af[i], bf[j], acc[i][j], 0, 0, 0);
  }

#pragma unroll
  for (int i = 0; i < 4; ++i)
#pragma unroll
    for (int j = 0; j < 4; ++j) {
      const int colb = n0 + wn * 64 + j * 16;
      const int col = colb + c;
      const int rowb = m0 + wm * 64 + i * 16 + g * 4;
      if (EPI == 3 && colb >= 1024) {
        const int bb = rowb >> 11, s0 = rowb & (SEQ - 1);
        union { u16 h4[4]; uint2 v; } pk;
#pragma unroll
        for (int r = 0; r < 4; ++r) pk.h4[r] = f2bf(acc[i][j][r]);
        *(uint2*)((u16*)Cv2 + ((long)(bb * 1024 + (col - 1024))) * SEQ + s0) = pk.v;
      } else {
#pragma unroll
        for (int r = 0; r < 4; ++r) {
          const int row = rowb + r;
          float v = acc[i][j][r];
          if (EPI == 1 || EPI == 3) {
            float pv = __shfl_xor(v, 1);
            int pos = row & (SEQ - 1);
            int fi = (col & (HDIM - 1)) >> 1;
            float cs = fc[pos * (HDIM / 2) + fi];
            float sn = fs[pos * (HDIM / 2) + fi];
            v = (col & 1) ? (pv * sn + v * cs) : (v * cs - pv * sn);
            if (EPI == 1) v *= 0.08838834764831845f;   // 1/sqrt(HD) folded into Q
          }
          if (EPI == 2)      ((float*)Cv)[(long)row * N + col] = v;
          else if (EPI == 3) ((u16*)Cv)[(long)row * KVD + col] = f2bf(v);
          else               ((u16*)Cv)[(long)row * N + col] = f2bf(v);
        }
      }
    }
}

// Flash attention, S^T orientation. grid(32, B*H). BQ=64 (4 waves x 16 q-rows), BK=64.
// LDS: sK 64x128 [0,8192) | sVT 128x64 [8192,16384) | per-wave P 16x64 [16384,20480). 40KB.
// Swizzle: 16B chunk k -> k^(row&7).
// Pipeline per tile j: QK(j) | sync1 | stageK(j+1) | softmax+PV(j) | sync2 | stageV(j+1).
__global__ __launch_bounds__(256, 4) void flash_attn(const u16* __restrict__ q, const u16* __restrict__ kk,
                                                     const u16* __restrict__ vt, u16* __restrict__ o) {
  __shared__ u16 smem[20480];
  const int tid = threadIdx.x;
  const int w = tid >> 6, l = tid & 63, g = (l >> 4) & 3, c = l & 15;
  const int bh = blockIdx.y, b = bh >> 5, h = bh & 31, kvh = h >> 2;
  const int q0 = (31 - blockIdx.x) * 64;           // heavy (causal) blocks first

  const u16* qg = q  + (long)(b * SEQ + q0) * DIMM + h * HDIM;
  const u16* kg = kk + (long)b * SEQ * KVD + kvh * HDIM;
  const u16* vg = vt + (long)(b * KVD + kvh * HDIM) * SEQ;   // V^T rows d, stride SEQ

  const int r4 = l >> 4, ka16 = l & 15, r8 = l >> 3, ka8 = l & 7;

  { // stage Q 64x128 swizzled into sK region
#pragma unroll
    for (int cc = 0; cc < 4; ++cc) {
      int row = cc * 16 + w * 4 + r4;
      gload_lds16(qg + (long)row * DIMM + ((ka16 ^ (row & 7)) * 8), &smem[(cc * 16 + w * 4) * 128]);
    }
  }
  __syncthreads();
  bf16x8 qf[4];                                     // B-operand frags: Q[q=c][dim], rows w*16+c
#pragma unroll
  for (int t = 0; t < 4; ++t)
    qf[t] = *(const bf16x8*)&smem[(w * 16 + c) * 128 + ((t * 4 + g) ^ (c & 7)) * 8];
  __syncthreads();                                  // qf reads done before K0 overwrite

  u16* sP = &smem[16384 + w * 1024];                // per-wave 16x64 P tile
  floatx4 oacc[8] = {};
  float mrow = -3e38f, lrow = 0.f;
  const int nkt = (q0 + 64) >> 6;
  const int qwave = q0 + w * 16;

  // prologue: stage K(0), V(0)
#pragma unroll
  for (int cc = 0; cc < 4; ++cc) {
    int srow = cc * 16 + w * 4 + r4;
    gload_lds16(kg + (long)srow * KVD + ((ka16 ^ (srow & 7)) * 8), &smem[(cc * 16 + w * 4) * 128]);
  }
#pragma unroll
  for (int cc = 0; cc < 4; ++cc) {
    int drow = cc * 32 + w * 8 + r8;
    gload_lds16(vg + (long)drow * SEQ + ((ka8 ^ (drow & 7)) * 8), &smem[8192 + (cc * 32 + w * 8) * 64]);
  }
  __syncthreads();                                  // drain K0,V0

  for (int j = 0; j < nkt; ++j) {
    // St = K * Q^T : frag rows = s (g*4+r), cols = q (c). Scores pre-scaled (Q epilogue).
    floatx4 sc[4] = {};
#pragma unroll
    for (int ms = 0; ms < 4; ++ms) {
      bf16x8 kf[4];
#pragma unroll
      for (int t = 0; t < 4; ++t)
        kf[t] = *(const bf16x8*)&smem[(ms * 16 + c) * 128 + ((t * 4 + g) ^ (c & 7)) * 8];
#pragma unroll
      for (int t = 0; t < 4; ++t)
        sc[ms] = __builtin_amdgcn_mfma_f32_16x16x32_bf16(kf[t], qf[t], sc[ms], 0, 0, 0);
    }
    __syncthreads();                                // Kbuf free; drains V(j)

    if (j + 1 < nkt) {                              // stage K(j+1) — drains at sync2
#pragma unroll
      for (int cc = 0; cc < 4; ++cc) {
        int srow = cc * 16 + w * 4 + r4;
        gload_lds16(kg + (long)((j + 1) * 64 + srow) * KVD + ((ka16 ^ (srow & 7)) * 8),
                    &smem[(cc * 16 + w * 4) * 128]);
      }
    }

    { // softmax (per-lane row q = c) + P pack
      const bool needMask = (j * 64 + 63) > qwave;  // wave-uniform (last tile only)
      const int qv = qwave + c;
      float mx = -3e38f;
#pragma unroll
      for (int ms = 0; ms < 4; ++ms) {
        const int sbase = j * 64 + ms * 16 + g * 4;
#pragma unroll
        for (int r = 0; r < 4; ++r) {
          float v = sc[ms][r];
          if (needMask && (sbase + r > qv)) v = -1e9f;
          sc[ms][r] = v;
          mx = fmaxf(mx, v);
        }
      }
      mx = fmaxf(mx, __shfl_xor(mx, 16));
      mx = fmaxf(mx, __shfl_xor(mx, 32));
      const float mnew = fmaxf(mrow, mx);
      const float alpha = __expf(mrow - mnew);
      mrow = mnew;
      float rs = 0.f;
#pragma unroll
      for (int ms = 0; ms < 4; ++ms)
#pragma unroll
        for (int r = 0; r < 4; ++r) {
          float p = __expf(sc[ms][r] - mnew);
          sc[ms][r] = p;
          rs += p;
        }
      rs += __shfl_xor(rs, 16);
      rs += __shfl_xor(rs, 32);
      lrow = lrow * alpha + rs;
#pragma unroll
      for (int md = 0; md < 8; ++md) oacc[md] *= alpha;
#pragma unroll
      for (int ms = 0; ms < 4; ++ms) {              // pack P (bf16) to per-wave LDS tile
        u32 lo = (u32)f2bf(sc[ms][0]) | ((u32)f2bf(sc[ms][1]) << 16);
        u32 hi = (u32)f2bf(sc[ms][2]) | ((u32)f2bf(sc[ms][3]) << 16);
        uint2 val; val.x = lo; val.y = hi;
        const int sc16 = ms * 2 + (g >> 1);
        *(uint2*)&sP[c * 64 + ((sc16 ^ (c & 7)) * 8) + (g & 1) * 4] = val;
      }
    }

    // O^T += V^T * P^T   (V(j) drained at sync1; P same-wave LDS order)
    bf16x8 pf[2];
#pragma unroll
    for (int kb2 = 0; kb2 < 2; ++kb2)
      pf[kb2] = *(const bf16x8*)&sP[c * 64 + (((kb2 * 4 + g) ^ (c & 7)) * 8)];
#pragma unroll
    for (int md = 0; md < 8; ++md)
#pragma unroll
      for (int kb2 = 0; kb2 < 2; ++kb2) {
        bf16x8 vf = *(const bf16x8*)&smem[8192 + (md * 16 + c) * 64 + (((kb2 * 4 + g) ^ (c & 7)) * 8)];
        oacc[md] = __builtin_amdgcn_mfma_f32_16x16x32_bf16(vf, pf[kb2], oacc[md], 0, 0, 0);
      }
    __syncthreads();                                // Vbuf free; drains K(j+1)

    if (j + 1 < nkt) {                              // stage V(j+1) — drains at next sync1
#pragma unroll
      for (int cc = 0; cc < 4; ++cc) {
        int drow = cc * 32 + w * 8 + r8;
        gload_lds16(vg + (long)drow * SEQ + (j + 1) * 64 + ((ka8 ^ (drow & 7)) * 8),
                    &smem[8192 + (cc * 32 + w * 8) * 64]);
      }
    }
  }

  // epilogue: O^T frag -> O row-major; lane: q = c, d = md*16 + g*4 + r
  u16* ob = o + (long)(b * SEQ + q0 + w * 16) * DIMM + h * HDIM;
  const float inv = 1.f / lrow;
#pragma unroll
  for (int md = 0; md < 8; ++md) {
    union { u16 h4[4]; uint2 v; } pk;
#pragma unroll
    for (int r = 0; r < 4; ++r) pk.h4[r] = f2bf(oacc[md][r] * inv);
    *(uint2*)&ob[(long)c * DIMM + md * 16 + g * 4] = pk.v;
  }
}

extern "C" void kernel_launch(void* const* d_in, const int* in_sizes, int n_in,
                              void* d_out, int out_size, void* d_ws, size_t ws_size,
                              hipStream_t stream) {
  (void)in_sizes; (void)n_in; (void)out_size; (void)ws_size;
  const float* x  = (const float*)d_in[0];
  const float* wq = (const float*)d_in[1];
  const float* wk = (const float*)d_in[2];
  const float* wv = (const float*)d_in[3];
  const float* wo = (const float*)d_in[4];
  const float* fc = (const float*)d_in[5];
  const float* fs = (const float*)d_in[6];

  u16* xb  = (u16*)d_ws;            // 16777216
  u16* w16 = xb  + 16777216;        // 16777216
  u16* qb  = w16 + 16777216;        // 16777216
  u16* kb  = qb  + 16777216;        //  4194304
  u16* vT  = kb  + 4194304;         //  4194304  V^T [2][1024][2048]
  u16* ab  = vT  + 4194304;         // 16777216

  const int M = NB * SEQ;           // 4096

  cast_f2bf_kernel<<<16777216 / 2048, 256, 0, stream>>>(x,  xb,  16777216);
  cast_f2bf_kernel<<<16777216 / 2048, 256, 0, stream>>>(wq, w16, 16777216);
  gemm_nt<1><<<dim3(32, 32), 256, 0, stream>>>(xb, w16, qb, nullptr, M, DIMM, DIMM, fc, fs);
  cast_f2bf_kernel<<<4194304 / 2048, 256, 0, stream>>>(wk, w16, 4194304);
  cast_f2bf_kernel<<<4194304 / 2048, 256, 0, stream>>>(wv, w16 + 4194304, 4194304);
  gemm_nt<3><<<dim3(16, 32), 256, 0, stream>>>(xb, w16, kb, vT, M, 2048, DIMM, fc, fs);
  flash_attn<<<dim3(32, 64), 256, 0, stream>>>(qb, kb, vT, ab);
  cast_f2bf_kernel<<<16777216 / 2048, 256, 0, stream>>>(wo, w16, 16777216);
  gemm_nt<2><<<dim3(32, 32), 256, 0, stream>>>(ab, w16, d_out, nullptr, M, DIMM, DIMM, nullptr, nullptr);
}